// Round 1
// baseline (4750.616 us; speedup 1.0000x reference)
//
#include <hip/hip_runtime.h>
#include <math.h>

#define NB 8
#define NN 2048
#define ND 128
#define NITER 32

// eps = blur^2 = (5e-5)^2 = 2.5e-9, as f32 like the reference
#define EPS_F   2.5e-9f
#define RCP_EPS (1.0f / EPS_F)
#define HSCALE  (0.5f * RCP_EPS)
#define LNEG    (-7.624618986159399f)   /* loga = logb = -log(2048) */

// Scaled-domain math (F = f/eps etc., M_ij = dot_ij/eps, h_i = 0.5*|x_i|^2/eps):
//   f-pass:  Fa_i = LNEG - lse_j(Gt_j + M_ij)            (Fa = loga + F - hx)
//   g-pass:  Gt_j = LNEG - lse_i(Fa_i + M_ij)            (Gt = logb + G - hy)
//   sym:     P'_i = 0.5*(P_i + h_i - lse_j(Pa_j + M_ij)),  Pa = loga + P - h
// Final: loss = eps * sum_{b,i}(F+G-Px-Py)/2048,  F = Fa - LNEG + hx, etc.

__device__ __forceinline__ void olse(float& m, float& s, float v) {
    if (v <= m) {
        s += __expf(v - m);
    } else {
        s = s * __expf(m - v) + 1.0f;   // m=-inf first time: 0*exp(-inf)=0
        m = v;
    }
}

__device__ __forceinline__ void olse_merge(float& m, float& s, float m2, float s2) {
    float mx = fmaxf(m, m2);
    s = s * __expf(m - mx) + s2 * __expf(m2 - mx);
    m = mx;
}

// ---------- preprocessing ----------

// wx[d] = sum_t x[0,t,d]^2  (reference quirk: batch 0 only), same for y
__global__ __launch_bounds__(256) void k_colsum(const float* __restrict__ x,
                                                const float* __restrict__ y,
                                                float* __restrict__ wx,
                                                float* __restrict__ wy) {
    const float* in = blockIdx.y ? y : x;
    float* w = blockIdx.y ? wy : wx;
    int d = blockIdx.x;
    int t = threadIdx.x;
    float sum = 0.f;
    for (int k = t; k < NN; k += 256) {
        float v = in[(size_t)k * ND + d];
        sum += v * v;
    }
    for (int off = 32; off > 0; off >>= 1) sum += __shfl_down(sum, off);
    __shared__ float ls[4];
    if ((t & 63) == 0) ls[t >> 6] = sum;
    __syncthreads();
    if (t == 0) w[d] = ls[0] + ls[1] + ls[2] + ls[3];
}

// X2 = x^2 / wx; h = 0.5*|X2 row|^2/eps
__global__ __launch_bounds__(128) void k_norm(const float* __restrict__ x,
                                              const float* __restrict__ y,
                                              const float* __restrict__ wx,
                                              const float* __restrict__ wy,
                                              float* __restrict__ X2,
                                              float* __restrict__ Y2,
                                              float* __restrict__ hx,
                                              float* __restrict__ hy) {
    int gx = blockIdx.x;                 // b*NN + i
    const float* in = blockIdx.y ? y : x;
    const float* w  = blockIdx.y ? wy : wx;
    float* o = blockIdx.y ? Y2 : X2;
    float* h = blockIdx.y ? hy : hx;
    int d = threadIdx.x;
    size_t base = (size_t)gx * ND;
    float v = in[base + d];
    float v2 = (v * v) / w[d];
    o[base + d] = v2;
    float sq = v2 * v2;
    for (int off = 32; off > 0; off >>= 1) sq += __shfl_down(sq, off);
    __shared__ float ls[2];
    if ((d & 63) == 0) ls[d >> 6] = sq;
    __syncthreads();
    if (d == 0) h[gx] = (ls[0] + ls[1]) * HSCALE;
}

__global__ __launch_bounds__(256) void k_init(const float* __restrict__ hx,
                                              const float* __restrict__ hy,
                                              float* __restrict__ Gt,
                                              float* __restrict__ Px, float* __restrict__ Pax,
                                              float* __restrict__ Py, float* __restrict__ Pay) {
    int tid = blockIdx.x * 256 + threadIdx.x;
    Gt[tid]  = LNEG - hy[tid];
    Px[tid]  = 0.f;
    Py[tid]  = 0.f;
    Pax[tid] = LNEG - hx[tid];
    Pay[tid] = LNEG - hy[tid];
}

// ---------- GEMM: C[b][i][j] = dot(A[b][i,:], B[b][j,:]) / eps ----------
// 128x128 tile, BK=32, 256 threads, 8x8 acc/thread (split 4+4 for coalescing)
__global__ __launch_bounds__(256) void k_gemm(const float* __restrict__ A,
                                              const float* __restrict__ B,
                                              float* __restrict__ C) {
    __shared__ float As[32][132];
    __shared__ float Bs[32][132];
    int bi = blockIdx.x, bj = blockIdx.y, b = blockIdx.z;
    const float* Ab = A + ((size_t)b * NN + (size_t)bi * 128) * ND;
    const float* Bb = B + ((size_t)b * NN + (size_t)bj * 128) * ND;
    int t = threadIdx.x;
    int tx = t & 15, ty = t >> 4;
    float acc[8][8];
#pragma unroll
    for (int i = 0; i < 8; ++i)
#pragma unroll
        for (int j = 0; j < 8; ++j) acc[i][j] = 0.f;
    int lr = t >> 3;            // 0..31
    int kq = (t & 7) << 2;      // k-quad
    for (int kt = 0; kt < ND; kt += 32) {
        __syncthreads();
#pragma unroll
        for (int s2 = 0; s2 < 4; ++s2) {
            int r = lr + (s2 << 5);
            float4 av = *(const float4*)(Ab + (size_t)r * ND + kt + kq);
            As[kq + 0][r] = av.x; As[kq + 1][r] = av.y; As[kq + 2][r] = av.z; As[kq + 3][r] = av.w;
            float4 bv = *(const float4*)(Bb + (size_t)r * ND + kt + kq);
            Bs[kq + 0][r] = bv.x; Bs[kq + 1][r] = bv.y; Bs[kq + 2][r] = bv.z; Bs[kq + 3][r] = bv.w;
        }
        __syncthreads();
#pragma unroll
        for (int k = 0; k < 32; ++k) {
            float a[8], bb[8];
            *(float4*)(a + 0)  = *(const float4*)&As[k][4 * ty];
            *(float4*)(a + 4)  = *(const float4*)&As[k][64 + 4 * ty];
            *(float4*)(bb + 0) = *(const float4*)&Bs[k][4 * tx];
            *(float4*)(bb + 4) = *(const float4*)&Bs[k][64 + 4 * tx];
#pragma unroll
            for (int i = 0; i < 8; ++i)
#pragma unroll
                for (int j = 0; j < 8; ++j)
                    acc[i][j] = fmaf(a[i], bb[j], acc[i][j]);
        }
    }
#pragma unroll
    for (int i = 0; i < 8; ++i) {
        int m = ((i & 4) << 4) + 4 * ty + (i & 3);   // 0..63 / 64..127
        float* cp = C + ((size_t)b * NN + (size_t)bi * 128 + m) * NN + (size_t)bj * 128;
        float4 lo = { acc[i][0] * RCP_EPS, acc[i][1] * RCP_EPS, acc[i][2] * RCP_EPS, acc[i][3] * RCP_EPS };
        float4 hi = { acc[i][4] * RCP_EPS, acc[i][5] * RCP_EPS, acc[i][6] * RCP_EPS, acc[i][7] * RCP_EPS };
        *(float4*)(cp + 4 * tx) = lo;
        *(float4*)(cp + 64 + 4 * tx) = hi;
    }
}

// ---------- row pass: f-update (mode 0) + both sym updates (modes 1,2) ----------
__global__ __launch_bounds__(256) void k_rowpass(
    const float* __restrict__ Mxy, const float* __restrict__ Mxx, const float* __restrict__ Myy,
    const float* __restrict__ Gt, float* __restrict__ Fa,
    const float* __restrict__ Px_o, const float* __restrict__ Pax_o,
    float* __restrict__ Px_n, float* __restrict__ Pax_n,
    const float* __restrict__ Py_o, const float* __restrict__ Pay_o,
    float* __restrict__ Py_n, float* __restrict__ Pay_n,
    const float* __restrict__ hx, const float* __restrict__ hy) {
    int gx = blockIdx.x;        // group-relative b*NN + i
    int mode = blockIdx.y;
    int brel = gx >> 11;
    const float* mat = (mode == 0) ? Mxy : (mode == 1) ? Mxx : Myy;
    const float* vecbase = (mode == 0) ? Gt : (mode == 1) ? Pax_o : Pay_o;
    const float* row = mat + ((size_t)gx << 11);
    const float* v = vecbase + ((size_t)brel << 11);
    int t = threadIdx.x;
    float m = -INFINITY, s = 0.f;
#pragma unroll
    for (int base = 0; base < NN; base += 1024) {
        float4 mv = *(const float4*)(row + base + 4 * t);
        float4 vv = *(const float4*)(v + base + 4 * t);
        olse(m, s, mv.x + vv.x);
        olse(m, s, mv.y + vv.y);
        olse(m, s, mv.z + vv.z);
        olse(m, s, mv.w + vv.w);
    }
    for (int off = 32; off > 0; off >>= 1)
        olse_merge(m, s, __shfl_down(m, off), __shfl_down(s, off));
    __shared__ float lm[4], lss[4];
    if ((t & 63) == 0) { lm[t >> 6] = m; lss[t >> 6] = s; }
    __syncthreads();
    if (t == 0) {
        for (int w2 = 1; w2 < 4; ++w2) olse_merge(m, s, lm[w2], lss[w2]);
        float lse = m + logf(s);
        if (mode == 0) {
            Fa[gx] = LNEG - lse;
        } else if (mode == 1) {
            float pn = 0.5f * (Px_o[gx] + hx[gx] - lse);
            Px_n[gx] = pn;
            Pax_n[gx] = LNEG + pn - hx[gx];
        } else {
            float pn = 0.5f * (Py_o[gx] + hy[gx] - lse);
            Py_n[gx] = pn;
            Pay_n[gx] = LNEG + pn - hy[gx];
        }
    }
}

// ---------- column pass (g-update), partials over 8 row-chunks ----------
__global__ __launch_bounds__(256) void k_colpass(const float* __restrict__ M,
                                                 const float* __restrict__ Fa,
                                                 float2* __restrict__ part) {
    int tile = blockIdx.x, chunk = blockIdx.y, b = blockIdx.z;
    int t = threadIdx.x;
    int lane = t & 63, w = t >> 6;
    const float* base = M + ((size_t)b << 22) + ((size_t)(chunk << 8) << 11) + tile * 256 + 4 * lane;
    const float* fa = Fa + ((size_t)b << 11) + (chunk << 8);
    float m0 = -INFINITY, m1 = -INFINITY, m2 = -INFINITY, m3 = -INFINITY;
    float s0 = 0.f, s1 = 0.f, s2 = 0.f, s3 = 0.f;
    for (int r = w; r < 256; r += 4) {
        float4 mv = *(const float4*)(base + ((size_t)r << 11));
        float fv = fa[r];
        olse(m0, s0, fv + mv.x);
        olse(m1, s1, fv + mv.y);
        olse(m2, s2, fv + mv.z);
        olse(m3, s3, fv + mv.w);
    }
    __shared__ float lm[4][256], lss[4][256];
    int slot = lane * 4;
    lm[w][slot + 0] = m0; lss[w][slot + 0] = s0;
    lm[w][slot + 1] = m1; lss[w][slot + 1] = s1;
    lm[w][slot + 2] = m2; lss[w][slot + 2] = s2;
    lm[w][slot + 3] = m3; lss[w][slot + 3] = s3;
    __syncthreads();
    float M2 = lm[0][t], S2 = lss[0][t];
    for (int ww = 1; ww < 4; ++ww) olse_merge(M2, S2, lm[ww][t], lss[ww][t]);
    int j = tile * 256 + t;
    part[(((size_t)b << 11) + j) * 8 + chunk] = make_float2(M2, S2);
}

__global__ __launch_bounds__(256) void k_combine(const float2* __restrict__ part,
                                                 float* __restrict__ Gt) {
    int tid = blockIdx.x * 256 + threadIdx.x;
    const float2* p = part + ((size_t)tid << 3);
    float m = p[0].x, s = p[0].y;
#pragma unroll
    for (int c = 1; c < 8; ++c) olse_merge(m, s, p[c].x, p[c].y);
    Gt[tid] = LNEG - (m + logf(s));
}

// ---------- final reduction ----------
__global__ __launch_bounds__(256) void k_final(const float* __restrict__ Fa, const float* __restrict__ Gt,
                                               const float* __restrict__ Px, const float* __restrict__ Py,
                                               const float* __restrict__ hx, const float* __restrict__ hy,
                                               float* __restrict__ out) {
    int t = threadIdx.x;
    double acc = 0.0;
    for (int i = t; i < NB * NN; i += 256) {
        acc += (double)(Fa[i] + hx[i]) + (double)(Gt[i] + hy[i])
             - (double)Px[i] - (double)Py[i];
    }
    __shared__ double ld[256];
    ld[t] = acc;
    __syncthreads();
    for (int off = 128; off > 0; off >>= 1) {
        if (t < off) ld[t] += ld[t + off];
        __syncthreads();
    }
    if (t == 0) {
        double total = ld[0] - 2.0 * (double)LNEG * (double)(NB * NN);
        out[0] = (float)((double)EPS_F * total / (double)NN);
    }
}

extern "C" void kernel_launch(void* const* d_in, const int* in_sizes, int n_in,
                              void* d_out, int out_size, void* d_ws, size_t ws_size,
                              hipStream_t stream) {
    (void)in_sizes; (void)n_in; (void)out_size;
    const float* x = (const float*)d_in[0];
    const float* y = (const float*)d_in[1];
    float* out = (float*)d_out;

    char* ws = (char*)d_ws;
    size_t off = 0;
    auto alloc = [&](size_t bytes) -> char* {
        char* p = ws + off;
        off += (bytes + 255) & ~(size_t)255;
        return p;
    };

    float* X2 = (float*)alloc((size_t)NB * NN * ND * 4);
    float* Y2 = (float*)alloc((size_t)NB * NN * ND * 4);
    float* wx = (float*)alloc(ND * 4);
    float* wy = (float*)alloc(ND * 4);
    float* hx = (float*)alloc((size_t)NB * NN * 4);
    float* hy = (float*)alloc((size_t)NB * NN * 4);
    float* Fa = (float*)alloc((size_t)NB * NN * 4);
    float* Gt = (float*)alloc((size_t)NB * NN * 4);
    float *Pxb[2], *Paxb[2], *Pyb[2], *Payb[2];
    for (int i = 0; i < 2; ++i) {
        Pxb[i]  = (float*)alloc((size_t)NB * NN * 4);
        Paxb[i] = (float*)alloc((size_t)NB * NN * 4);
        Pyb[i]  = (float*)alloc((size_t)NB * NN * 4);
        Payb[i] = (float*)alloc((size_t)NB * NN * 4);
    }
    float2* part = (float2*)alloc((size_t)NB * NN * 8 * sizeof(float2));

    // Batch-group size: shrink if workspace is small (matrices rebuilt per group)
    size_t small_end = off;
    size_t matBytes = (size_t)NN * NN * 4;           // 16 MB
    int G = NB;
    while (G > 1 && small_end + 3 * matBytes * (size_t)G + 4096 > ws_size) G >>= 1;
    float* Mxy = (float*)alloc(matBytes * (size_t)G);
    float* Mxx = (float*)alloc(matBytes * (size_t)G);
    float* Myy = (float*)alloc(matBytes * (size_t)G);

    k_colsum<<<dim3(ND, 2), 256, 0, stream>>>(x, y, wx, wy);
    k_norm<<<dim3(NB * NN, 2), 128, 0, stream>>>(x, y, wx, wy, X2, Y2, hx, hy);
    k_init<<<dim3(NB * NN / 256), 256, 0, stream>>>(hx, hy, Gt, Pxb[0], Paxb[0], Pyb[0], Payb[0]);

    for (int b0 = 0; b0 < NB; b0 += G) {
        size_t po = (size_t)b0 * NN;
        const float* X2g = X2 + po * ND;
        const float* Y2g = Y2 + po * ND;
        k_gemm<<<dim3(16, 16, G), 256, 0, stream>>>(X2g, Y2g, Mxy);
        k_gemm<<<dim3(16, 16, G), 256, 0, stream>>>(X2g, X2g, Mxx);
        k_gemm<<<dim3(16, 16, G), 256, 0, stream>>>(Y2g, Y2g, Myy);
        int cur = 0;
        for (int it = 0; it < NITER; ++it) {
            k_rowpass<<<dim3(G * NN, 3), 256, 0, stream>>>(
                Mxy, Mxx, Myy,
                Gt + po, Fa + po,
                Pxb[cur] + po, Paxb[cur] + po, Pxb[1 - cur] + po, Paxb[1 - cur] + po,
                Pyb[cur] + po, Payb[cur] + po, Pyb[1 - cur] + po, Payb[1 - cur] + po,
                hx + po, hy + po);
            k_colpass<<<dim3(8, 8, G), 256, 0, stream>>>(Mxy, Fa + po, part + po * 8);
            k_combine<<<dim3(G * NN / 256), 256, 0, stream>>>(part + po * 8, Gt + po);
            cur ^= 1;
        }
    }
    // NITER even -> final sym potentials are in buffer 0
    k_final<<<dim3(1), 256, 0, stream>>>(Fa, Gt, Pxb[0], Pyb[0], hx, hy, out);
}

// Round 2
// 2350.982 us; speedup vs baseline: 2.0207x; 2.0207x over previous
//
#include <hip/hip_runtime.h>
#include <math.h>

#define NB 8
#define NN 2048
#define ND 128
#define NITER 32

// eps = blur^2 = (5e-5)^2 = 2.5e-9
#define EPS_F   2.5e-9f
#define HSCALE  (0.5f / EPS_F)
#define LNEG    (-7.624618986159399f)   /* loga = logb = -log(2048) */

typedef unsigned short ushort8v __attribute__((ext_vector_type(8)));
typedef unsigned short ushort4v __attribute__((ext_vector_type(4)));

// Scaled-domain math (F = f/eps etc., M_ij = dot_ij/eps, h_i = 0.5*|x_i|^2/eps):
//   f-pass:  Fa_i = LNEG - lse_j(Gt_j + M_ij)            (Fa = loga + F - hx)
//   g-pass:  Gt_j = LNEG - lse_i(Fa_i + M_ij)            (Gt = logb + G - hy)
//   sym:     P'_i = 0.5*(P_i + h_i - lse_j(Pa_j + M_ij)),  Pa = loga + P - h
// M stored quantized: M_ij = q_ij * S_row(i),  q in u16, S = |x_i|*nmax/(65535*eps).

__device__ __forceinline__ void olse(float& m, float& s, float v) {
    if (v <= m) {
        s += __expf(v - m);
    } else {
        s = s * __expf(m - v) + 1.0f;   // m=-inf first time: 0*exp(-inf)=0
        m = v;
    }
}

__device__ __forceinline__ void olse_merge(float& m, float& s, float m2, float s2) {
    float mx = fmaxf(m, m2);
    s = s * __expf(m - mx) + s2 * __expf(m2 - mx);
    m = mx;
}

// ---------- preprocessing ----------

// wx[d] = sum_t x[0,t,d]^2  (reference quirk: batch 0 only), same for y
__global__ __launch_bounds__(256) void k_colsum(const float* __restrict__ x,
                                                const float* __restrict__ y,
                                                float* __restrict__ wx,
                                                float* __restrict__ wy) {
    const float* in = blockIdx.y ? y : x;
    float* w = blockIdx.y ? wy : wx;
    int d = blockIdx.x;
    int t = threadIdx.x;
    float sum = 0.f;
    for (int k = t; k < NN; k += 256) {
        float v = in[(size_t)k * ND + d];
        sum += v * v;
    }
    for (int off = 32; off > 0; off >>= 1) sum += __shfl_down(sum, off);
    __shared__ float ls[4];
    if ((t & 63) == 0) ls[t >> 6] = sum;
    __syncthreads();
    if (t == 0) w[d] = ls[0] + ls[1] + ls[2] + ls[3];
}

// X2 = x^2 / wx; h = 0.5*|X2 row|^2/eps; rn = |X2 row|
__global__ __launch_bounds__(128) void k_norm(const float* __restrict__ x,
                                              const float* __restrict__ y,
                                              const float* __restrict__ wx,
                                              const float* __restrict__ wy,
                                              float* __restrict__ X2,
                                              float* __restrict__ Y2,
                                              float* __restrict__ hx,
                                              float* __restrict__ hy,
                                              float* __restrict__ rnx,
                                              float* __restrict__ rny) {
    int gx = blockIdx.x;                 // b*NN + i
    const float* in = blockIdx.y ? y : x;
    const float* w  = blockIdx.y ? wy : wx;
    float* o  = blockIdx.y ? Y2 : X2;
    float* h  = blockIdx.y ? hy : hx;
    float* rn = blockIdx.y ? rny : rnx;
    int d = threadIdx.x;
    size_t base = (size_t)gx * ND;
    float v = in[base + d];
    float v2 = (v * v) / w[d];
    o[base + d] = v2;
    float sq = v2 * v2;
    for (int off = 32; off > 0; off >>= 1) sq += __shfl_down(sq, off);
    __shared__ float ls[2];
    if ((d & 63) == 0) ls[d >> 6] = sq;
    __syncthreads();
    if (d == 0) {
        float ss = ls[0] + ls[1];
        h[gx] = ss * HSCALE;
        rn[gx] = sqrtf(ss);
    }
}

// per-batch max row norm
__global__ __launch_bounds__(256) void k_batchmax(const float* __restrict__ rnx,
                                                  const float* __restrict__ rny,
                                                  float* __restrict__ nxmax,
                                                  float* __restrict__ nymax) {
    const float* rn = blockIdx.y ? rny : rnx;
    float* o = blockIdx.y ? nymax : nxmax;
    int b = blockIdx.x, t = threadIdx.x;
    float mx = 0.f;
    for (int i = t; i < NN; i += 256) mx = fmaxf(mx, rn[(size_t)b * NN + i]);
    for (int off = 32; off > 0; off >>= 1) mx = fmaxf(mx, __shfl_down(mx, off));
    __shared__ float ls[4];
    if ((t & 63) == 0) ls[t >> 6] = mx;
    __syncthreads();
    if (t == 0) o[b] = fmaxf(fmaxf(ls[0], ls[1]), fmaxf(ls[2], ls[3]));
}

// per-row quantization constants for the three matrices
__global__ __launch_bounds__(256) void k_scales(const float* __restrict__ rnx,
                                                const float* __restrict__ rny,
                                                const float* __restrict__ nxmax,
                                                const float* __restrict__ nymax,
                                                float* __restrict__ invxy, float* __restrict__ sxy,
                                                float* __restrict__ invxx, float* __restrict__ sxx,
                                                float* __restrict__ invyy, float* __restrict__ syy) {
    int i = blockIdx.x * 256 + threadIdx.x;
    int b = i >> 11;
    float nx = rnx[i], ny = rny[i];
    float bxy = nx * nymax[b];
    float bxx = nx * nxmax[b];
    float byy = ny * nymax[b];
    invxy[i] = 65535.f / bxy; sxy[i] = bxy / (65535.f * EPS_F);
    invxx[i] = 65535.f / bxx; sxx[i] = bxx / (65535.f * EPS_F);
    invyy[i] = 65535.f / byy; syy[i] = byy / (65535.f * EPS_F);
}

__global__ __launch_bounds__(256) void k_init(const float* __restrict__ hx,
                                              const float* __restrict__ hy,
                                              float* __restrict__ Gt,
                                              float* __restrict__ Px, float* __restrict__ Pax,
                                              float* __restrict__ Py, float* __restrict__ Pay) {
    int tid = blockIdx.x * 256 + threadIdx.x;
    Gt[tid]  = LNEG - hy[tid];
    Px[tid]  = 0.f;
    Py[tid]  = 0.f;
    Pax[tid] = LNEG - hx[tid];
    Pay[tid] = LNEG - hy[tid];
}

// ---------- GEMM: Q[b][i][j] = quant( dot(A[b][i,:], B[b][j,:]) * invA[i] ) ----------
// 128x128 tile, BK=32, 256 threads, 8x8 acc/thread
__global__ __launch_bounds__(256) void k_gemm(const float* __restrict__ A,
                                              const float* __restrict__ B,
                                              const float* __restrict__ invA,
                                              unsigned short* __restrict__ C) {
    __shared__ float As[32][132];
    __shared__ float Bs[32][132];
    int bi = blockIdx.x, bj = blockIdx.y, b = blockIdx.z;
    const float* Ab = A + ((size_t)b * NN + (size_t)bi * 128) * ND;
    const float* Bb = B + ((size_t)b * NN + (size_t)bj * 128) * ND;
    int t = threadIdx.x;
    int tx = t & 15, ty = t >> 4;
    float acc[8][8];
#pragma unroll
    for (int i = 0; i < 8; ++i)
#pragma unroll
        for (int j = 0; j < 8; ++j) acc[i][j] = 0.f;
    int lr = t >> 3;            // 0..31
    int kq = (t & 7) << 2;      // k-quad
    for (int kt = 0; kt < ND; kt += 32) {
        __syncthreads();
#pragma unroll
        for (int s2 = 0; s2 < 4; ++s2) {
            int r = lr + (s2 << 5);
            float4 av = *(const float4*)(Ab + (size_t)r * ND + kt + kq);
            As[kq + 0][r] = av.x; As[kq + 1][r] = av.y; As[kq + 2][r] = av.z; As[kq + 3][r] = av.w;
            float4 bv = *(const float4*)(Bb + (size_t)r * ND + kt + kq);
            Bs[kq + 0][r] = bv.x; Bs[kq + 1][r] = bv.y; Bs[kq + 2][r] = bv.z; Bs[kq + 3][r] = bv.w;
        }
        __syncthreads();
#pragma unroll
        for (int k = 0; k < 32; ++k) {
            float a[8], bb[8];
            *(float4*)(a + 0)  = *(const float4*)&As[k][4 * ty];
            *(float4*)(a + 4)  = *(const float4*)&As[k][64 + 4 * ty];
            *(float4*)(bb + 0) = *(const float4*)&Bs[k][4 * tx];
            *(float4*)(bb + 4) = *(const float4*)&Bs[k][64 + 4 * tx];
#pragma unroll
            for (int i = 0; i < 8; ++i)
#pragma unroll
                for (int j = 0; j < 8; ++j)
                    acc[i][j] = fmaf(a[i], bb[j], acc[i][j]);
        }
    }
#pragma unroll
    for (int i = 0; i < 8; ++i) {
        int m = ((i & 4) << 4) + 4 * ty + (i & 3);   // 0..63 / 64..127
        size_t grow = (size_t)b * NN + (size_t)bi * 128 + m;
        float iv = invA[grow];
        unsigned short* cp = C + grow * NN + (size_t)bj * 128;
        ushort4v lo, hi;
#pragma unroll
        for (int j = 0; j < 4; ++j) {
            int ql = (int)fmaf(acc[i][j], iv, 0.5f);
            int qh = (int)fmaf(acc[i][4 + j], iv, 0.5f);
            lo[j] = (unsigned short)(ql > 65535 ? 65535 : ql);
            hi[j] = (unsigned short)(qh > 65535 ? 65535 : qh);
        }
        *(ushort4v*)(cp + 4 * tx) = lo;
        *(ushort4v*)(cp + 64 + 4 * tx) = hi;
    }
}

// ---------- row pass: wave-per-row, branch-free two-pass lse ----------
__global__ __launch_bounds__(256) void k_rowpass(
    const unsigned short* __restrict__ Qxy, const unsigned short* __restrict__ Qxx,
    const unsigned short* __restrict__ Qyy,
    const float* __restrict__ Sxy, const float* __restrict__ Sxx, const float* __restrict__ Syy,
    const float* __restrict__ Gt, float* __restrict__ Fa,
    const float* __restrict__ Px_o, const float* __restrict__ Pax_o,
    float* __restrict__ Px_n, float* __restrict__ Pax_n,
    const float* __restrict__ Py_o, const float* __restrict__ Pay_o,
    float* __restrict__ Py_n, float* __restrict__ Pay_n,
    const float* __restrict__ hx, const float* __restrict__ hy) {
    int lane = threadIdx.x & 63;
    int w    = threadIdx.x >> 6;
    int gx   = blockIdx.x * 4 + w;      // group-relative b*NN + i
    int mode = blockIdx.y;
    int brel = gx >> 11;
    const unsigned short* mat = (mode == 0) ? Qxy : (mode == 1) ? Qxx : Qyy;
    const float* sc = (mode == 0) ? Sxy : (mode == 1) ? Sxx : Syy;
    const float* vb = (mode == 0) ? Gt  : (mode == 1) ? Pax_o : Pay_o;
    const unsigned short* row = mat + ((size_t)gx << 11);
    const float* v = vb + ((size_t)brel << 11);
    float si = sc[gx];

    float vals[32];
#pragma unroll
    for (int k = 0; k < 4; ++k) {
        int e = (k << 9) + lane * 8;
        ushort8v q = *(const ushort8v*)(row + e);
        float4 va = *(const float4*)(v + e);
        float4 vc = *(const float4*)(v + e + 4);
        vals[k * 8 + 0] = fmaf((float)q[0], si, va.x);
        vals[k * 8 + 1] = fmaf((float)q[1], si, va.y);
        vals[k * 8 + 2] = fmaf((float)q[2], si, va.z);
        vals[k * 8 + 3] = fmaf((float)q[3], si, va.w);
        vals[k * 8 + 4] = fmaf((float)q[4], si, vc.x);
        vals[k * 8 + 5] = fmaf((float)q[5], si, vc.y);
        vals[k * 8 + 6] = fmaf((float)q[6], si, vc.z);
        vals[k * 8 + 7] = fmaf((float)q[7], si, vc.w);
    }
    float mx = vals[0];
#pragma unroll
    for (int i = 1; i < 32; ++i) mx = fmaxf(mx, vals[i]);
#pragma unroll
    for (int off = 32; off > 0; off >>= 1) mx = fmaxf(mx, __shfl_xor(mx, off));
    float s0 = 0.f, s1 = 0.f, s2 = 0.f, s3 = 0.f;
#pragma unroll
    for (int i = 0; i < 32; i += 4) {
        s0 += __expf(vals[i + 0] - mx);
        s1 += __expf(vals[i + 1] - mx);
        s2 += __expf(vals[i + 2] - mx);
        s3 += __expf(vals[i + 3] - mx);
    }
    float s = (s0 + s1) + (s2 + s3);
#pragma unroll
    for (int off = 32; off > 0; off >>= 1) s += __shfl_xor(s, off);
    if (lane == 0) {
        float lse = mx + logf(s);
        if (mode == 0) {
            Fa[gx] = LNEG - lse;
        } else if (mode == 1) {
            float pn = 0.5f * (Px_o[gx] + hx[gx] - lse);
            Px_n[gx] = pn;
            Pax_n[gx] = LNEG + pn - hx[gx];
        } else {
            float pn = 0.5f * (Py_o[gx] + hy[gx] - lse);
            Py_n[gx] = pn;
            Pay_n[gx] = LNEG + pn - hy[gx];
        }
    }
}

// ---------- column pass (g-update), partials over 8 row-chunks ----------
__global__ __launch_bounds__(256) void k_colpass(const unsigned short* __restrict__ Q,
                                                 const float* __restrict__ S,
                                                 const float* __restrict__ Fa,
                                                 float2* __restrict__ part) {
    int tile = blockIdx.x, chunk = blockIdx.y, b = blockIdx.z;
    int t = threadIdx.x;
    int cg = t & 31, rt = t >> 5;
    const unsigned short* base = Q + ((size_t)b << 22) + (size_t)(chunk << 8) * NN + tile * 256 + cg * 8;
    const float* fa = Fa + ((size_t)b << 11) + (chunk << 8);
    const float* rs = S + ((size_t)b << 11) + (chunk << 8);
    float m[8], s[8];
#pragma unroll
    for (int j = 0; j < 8; ++j) { m[j] = -INFINITY; s[j] = 0.f; }
    for (int r = rt; r < 256; r += 8) {
        ushort8v q = *(const ushort8v*)(base + (size_t)r * NN);
        float f = fa[r];
        float sc = rs[r];
#pragma unroll
        for (int j = 0; j < 8; ++j)
            olse(m[j], s[j], fmaf((float)q[j], sc, f));
    }
    __shared__ float2 buf[8][256];
#pragma unroll
    for (int j = 0; j < 8; ++j) buf[rt][cg * 8 + j] = make_float2(m[j], s[j]);
    __syncthreads();
    float2 p = buf[0][t];
    float M2 = p.x, S2 = p.y;
#pragma unroll
    for (int ww = 1; ww < 8; ++ww) olse_merge(M2, S2, buf[ww][t].x, buf[ww][t].y);
    int j = tile * 256 + t;
    part[(((size_t)b << 11) + j) * 8 + chunk] = make_float2(M2, S2);
}

__global__ __launch_bounds__(256) void k_combine(const float2* __restrict__ part,
                                                 float* __restrict__ Gt) {
    int tid = blockIdx.x * 256 + threadIdx.x;
    const float2* p = part + ((size_t)tid << 3);
    float m = p[0].x, s = p[0].y;
#pragma unroll
    for (int c = 1; c < 8; ++c) olse_merge(m, s, p[c].x, p[c].y);
    Gt[tid] = LNEG - (m + logf(s));
}

// ---------- final reduction ----------
__global__ __launch_bounds__(256) void k_final(const float* __restrict__ Fa, const float* __restrict__ Gt,
                                               const float* __restrict__ Px, const float* __restrict__ Py,
                                               const float* __restrict__ hx, const float* __restrict__ hy,
                                               float* __restrict__ out) {
    int t = threadIdx.x;
    double acc = 0.0;
    for (int i = t; i < NB * NN; i += 256) {
        acc += (double)(Fa[i] + hx[i]) + (double)(Gt[i] + hy[i])
             - (double)Px[i] - (double)Py[i];
    }
    __shared__ double ld[256];
    ld[t] = acc;
    __syncthreads();
    for (int off = 128; off > 0; off >>= 1) {
        if (t < off) ld[t] += ld[t + off];
        __syncthreads();
    }
    if (t == 0) {
        double total = ld[0] - 2.0 * (double)LNEG * (double)(NB * NN);
        out[0] = (float)((double)EPS_F * total / (double)NN);
    }
}

extern "C" void kernel_launch(void* const* d_in, const int* in_sizes, int n_in,
                              void* d_out, int out_size, void* d_ws, size_t ws_size,
                              hipStream_t stream) {
    (void)in_sizes; (void)n_in; (void)out_size;
    const float* x = (const float*)d_in[0];
    const float* y = (const float*)d_in[1];
    float* out = (float*)d_out;

    char* ws = (char*)d_ws;
    size_t off = 0;
    auto alloc = [&](size_t bytes) -> char* {
        char* p = ws + off;
        off += (bytes + 255) & ~(size_t)255;
        return p;
    };

    float* X2 = (float*)alloc((size_t)NB * NN * ND * 4);
    float* Y2 = (float*)alloc((size_t)NB * NN * ND * 4);
    float* wx = (float*)alloc(ND * 4);
    float* wy = (float*)alloc(ND * 4);
    float* hx = (float*)alloc((size_t)NB * NN * 4);
    float* hy = (float*)alloc((size_t)NB * NN * 4);
    float* rnx = (float*)alloc((size_t)NB * NN * 4);
    float* rny = (float*)alloc((size_t)NB * NN * 4);
    float* nxmax = (float*)alloc(NB * 4);
    float* nymax = (float*)alloc(NB * 4);
    float* invxy = (float*)alloc((size_t)NB * NN * 4);
    float* sxy   = (float*)alloc((size_t)NB * NN * 4);
    float* invxx = (float*)alloc((size_t)NB * NN * 4);
    float* sxx   = (float*)alloc((size_t)NB * NN * 4);
    float* invyy = (float*)alloc((size_t)NB * NN * 4);
    float* syy   = (float*)alloc((size_t)NB * NN * 4);
    float* Fa = (float*)alloc((size_t)NB * NN * 4);
    float* Gt = (float*)alloc((size_t)NB * NN * 4);
    float *Pxb[2], *Paxb[2], *Pyb[2], *Payb[2];
    for (int i = 0; i < 2; ++i) {
        Pxb[i]  = (float*)alloc((size_t)NB * NN * 4);
        Paxb[i] = (float*)alloc((size_t)NB * NN * 4);
        Pyb[i]  = (float*)alloc((size_t)NB * NN * 4);
        Payb[i] = (float*)alloc((size_t)NB * NN * 4);
    }
    float2* part = (float2*)alloc((size_t)NB * NN * 8 * sizeof(float2));

    // Batch-group size: shrink if workspace is small (matrices rebuilt per group)
    size_t small_end = off;
    size_t matBytes = (size_t)NN * NN * 2;           // 8 MB (u16)
    int G = NB;
    while (G > 1 && small_end + 3 * matBytes * (size_t)G + 4096 > ws_size) G >>= 1;
    unsigned short* Qxy = (unsigned short*)alloc(matBytes * (size_t)G);
    unsigned short* Qxx = (unsigned short*)alloc(matBytes * (size_t)G);
    unsigned short* Qyy = (unsigned short*)alloc(matBytes * (size_t)G);

    k_colsum<<<dim3(ND, 2), 256, 0, stream>>>(x, y, wx, wy);
    k_norm<<<dim3(NB * NN, 2), 128, 0, stream>>>(x, y, wx, wy, X2, Y2, hx, hy, rnx, rny);
    k_batchmax<<<dim3(NB, 2), 256, 0, stream>>>(rnx, rny, nxmax, nymax);
    k_scales<<<dim3(NB * NN / 256), 256, 0, stream>>>(rnx, rny, nxmax, nymax,
                                                      invxy, sxy, invxx, sxx, invyy, syy);
    k_init<<<dim3(NB * NN / 256), 256, 0, stream>>>(hx, hy, Gt, Pxb[0], Paxb[0], Pyb[0], Payb[0]);

    for (int b0 = 0; b0 < NB; b0 += G) {
        size_t po = (size_t)b0 * NN;
        const float* X2g = X2 + po * ND;
        const float* Y2g = Y2 + po * ND;
        k_gemm<<<dim3(16, 16, G), 256, 0, stream>>>(X2g, Y2g, invxy + po, Qxy);
        k_gemm<<<dim3(16, 16, G), 256, 0, stream>>>(X2g, X2g, invxx + po, Qxx);
        k_gemm<<<dim3(16, 16, G), 256, 0, stream>>>(Y2g, Y2g, invyy + po, Qyy);
        int cur = 0;
        for (int it = 0; it < NITER; ++it) {
            k_rowpass<<<dim3(G * NN / 4, 3), 256, 0, stream>>>(
                Qxy, Qxx, Qyy,
                sxy + po, sxx + po, syy + po,
                Gt + po, Fa + po,
                Pxb[cur] + po, Paxb[cur] + po, Pxb[1 - cur] + po, Paxb[1 - cur] + po,
                Pyb[cur] + po, Payb[cur] + po, Pyb[1 - cur] + po, Payb[1 - cur] + po,
                hx + po, hy + po);
            k_colpass<<<dim3(8, 8, G), 256, 0, stream>>>(Qxy, sxy + po, Fa + po, part + po * 8);
            k_combine<<<dim3(G * NN / 256), 256, 0, stream>>>(part + po * 8, Gt + po);
            cur ^= 1;
        }
    }
    // NITER even -> final sym potentials are in buffer 0
    k_final<<<dim3(1), 256, 0, stream>>>(Fa, Gt, Pxb[0], Pyb[0], hx, hy, out);
}